// Round 9
// baseline (344.718 us; speedup 1.0000x reference)
//
#include <hip/hip_runtime.h>

// ---------------------------------------------------------------------------
// SupervisedGATEncoder: 2-layer GAT (4 heads x 64 -> BN -> ReLU -> 1 head x 32)
// + graph-mean prediction head.
//
// R9: cooperative-shfl aggs (R7/R8 — FAILED, ds_bpermute under divergence)
// reverted to R6's proven structures. Redundant exp removed instead by
// materializing edge weights edge-parallel: scatter (after gemm0) writes
// csr_dst + ew0[pos*4+h]; ew1_kernel (after gemm1) writes ew1[i]. Agg hot
// loops load weights (sequential per row) instead of gather+exp.
// ---------------------------------------------------------------------------

#define NEG_SLOPE 0.2f
#define BN_EPS 1e-5f

typedef __attribute__((ext_vector_type(8))) short bf16x8;
typedef __attribute__((ext_vector_type(4))) float f32x4;

__device__ __forceinline__ float bf2f(unsigned short u) {
  return __uint_as_float((unsigned)u << 16);
}
__device__ __forceinline__ unsigned short f2bf(float f) {
  unsigned u = __float_as_uint(f);
  u += 0x7fff + ((u >> 16) & 1);   // round-to-nearest-even
  return (unsigned short)(u >> 16);
}
__device__ __forceinline__ float lrelu(float x) {
  return x > 0.f ? x : NEG_SLOPE * x;
}

// ------------- W0 + W1 -> bf16, swizzled to MFMA B-fragment order ----------
__global__ __launch_bounds__(256) void w_swizzle_kernel(
    const float* __restrict__ W0, const float* __restrict__ W1,
    unsigned short* __restrict__ w0sw, unsigned short* __restrict__ w1sw) {
  int o = blockIdx.x * 256 + threadIdx.x;
  if (o < 32768) {
    int j = o & 7, l = (o >> 3) & 63, ks = (o >> 9) & 3,
        ci = (o >> 11) & 3, h = (o >> 13) & 3;
    int row = ks * 32 + (l >> 4) * 8 + j;
    int col = h * 64 + ci * 16 + (l & 15);
    w0sw[o] = f2bf(W0[row * 256 + col]);
  } else if (o < 40960) {
    int o2 = o - 32768;
    int j = o2 & 7, l = (o2 >> 3) & 63, ks = (o2 >> 9) & 7, ci = (o2 >> 12) & 1;
    int row = ks * 32 + (l >> 4) * 8 + j;
    int col = ci * 16 + (l & 15);
    w1sw[o2] = f2bf(W1[row * 32 + col]);
  }
}

// ---------------- GEMM0 (MFMA): h0[M,256] = x[M,128] @ W0[128,256] ---------
__global__ __launch_bounds__(256) void gemm0_mfma_kernel(
    const float* __restrict__ x, const unsigned short* __restrict__ w0sw,
    const float* __restrict__ a_src0, const float* __restrict__ a_dst0,
    unsigned short* __restrict__ h0bf, float* __restrict__ as0,
    float* __restrict__ ad0, int M) {
  __shared__ unsigned short Asw[16 * 64 * 8];   // 16 KB
  const int t = threadIdx.x;
  const int lane = t & 63;
  const int h = t >> 6;            // wave id == head
  const int row0 = blockIdx.x * 64;

  #pragma unroll
  for (int i = 0; i < 8; ++i) {
    int q = t + 256 * i;
    int r = q >> 5, c4 = q & 31;
    int gr = row0 + r;
    float4 v = make_float4(0.f, 0.f, 0.f, 0.f);
    if (gr < M) v = *reinterpret_cast<const float4*>(&x[(size_t)gr * 128 + c4 * 4]);
    int ks = c4 >> 3;
    int lane_hi = (c4 >> 1) & 3;
    int j0 = (c4 & 1) * 4;
    int slot = (r >> 4) * 4 + ks;
    int dlane = (r & 15) + 16 * lane_hi;
    ushort4 o;
    o.x = f2bf(v.x); o.y = f2bf(v.y); o.z = f2bf(v.z); o.w = f2bf(v.w);
    *reinterpret_cast<ushort4*>(&Asw[(slot * 64 + dlane) * 8 + j0]) = o;
  }
  __syncthreads();

  f32x4 acc[4][4] = {};
  const bf16x8* wp = reinterpret_cast<const bf16x8*>(w0sw);
  #pragma unroll
  for (int ks = 0; ks < 4; ++ks) {
    bf16x8 bfrag[4];
    #pragma unroll
    for (int ci = 0; ci < 4; ++ci)
      bfrag[ci] = wp[(h * 16 + ci * 4 + ks) * 64 + lane];
    #pragma unroll
    for (int ri = 0; ri < 4; ++ri) {
      bf16x8 af = *reinterpret_cast<const bf16x8*>(&Asw[((ri * 4 + ks) * 64 + lane) * 8]);
      #pragma unroll
      for (int ci = 0; ci < 4; ++ci)
        acc[ri][ci] = __builtin_amdgcn_mfma_f32_16x16x32_bf16(af, bfrag[ci], acc[ri][ci], 0, 0, 0);
    }
  }

  float av[4], dv[4];
  #pragma unroll
  for (int ci = 0; ci < 4; ++ci) {
    av[ci] = a_src0[h * 64 + ci * 16 + (lane & 15)];
    dv[ci] = a_dst0[h * 64 + ci * 16 + (lane & 15)];
  }
  const int mrow = (lane >> 4) * 4;
  #pragma unroll
  for (int ri = 0; ri < 4; ++ri) {
    #pragma unroll
    for (int r = 0; r < 4; ++r) {
      int gr = row0 + ri * 16 + mrow + r;
      float ps = acc[ri][0][r] * av[0] + acc[ri][1][r] * av[1] +
                 acc[ri][2][r] * av[2] + acc[ri][3][r] * av[3];
      float pd = acc[ri][0][r] * dv[0] + acc[ri][1][r] * dv[1] +
                 acc[ri][2][r] * dv[2] + acc[ri][3][r] * dv[3];
      #pragma unroll
      for (int off = 1; off < 16; off <<= 1) {
        ps += __shfl_xor(ps, off);
        pd += __shfl_xor(pd, off);
      }
      if (gr < M) {
        #pragma unroll
        for (int ci = 0; ci < 4; ++ci)
          h0bf[(size_t)gr * 256 + h * 64 + ci * 16 + (lane & 15)] = f2bf(acc[ri][ci][r]);
        if ((lane & 15) == 0) { as0[gr * 4 + h] = ps; ad0[gr * 4 + h] = pd; }
      }
    }
  }
}

// ------------- GEMM1 (MFMA): h1[M,32] = agg0bf[M,256] @ W1[256,32] ---------
__global__ __launch_bounds__(256) void gemm1_mfma_kernel(
    const unsigned short* __restrict__ agg0bf,
    const unsigned short* __restrict__ w1sw,
    const float* __restrict__ a_src1, const float* __restrict__ a_dst1,
    unsigned short* __restrict__ h1bf, float* __restrict__ as1,
    float* __restrict__ ad1, int M) {
  const int t = threadIdx.x;
  const int lane = t & 63;
  const int w = t >> 6;
  const int rbase = blockIdx.x * 64 + w * 16;
  const int arow = rbase + (lane & 15);
  const int ar = arow < M ? arow : M - 1;   // clamp: A row m only affects C row m
  const bf16x8* ap = reinterpret_cast<const bf16x8*>(agg0bf) + (size_t)ar * 32;
  const bf16x8* bp = reinterpret_cast<const bf16x8*>(w1sw);

  f32x4 acc[2] = {};
  #pragma unroll
  for (int ks = 0; ks < 8; ++ks) {
    bf16x8 af = ap[ks * 4 + (lane >> 4)];
    acc[0] = __builtin_amdgcn_mfma_f32_16x16x32_bf16(af, bp[(0 * 8 + ks) * 64 + lane], acc[0], 0, 0, 0);
    acc[1] = __builtin_amdgcn_mfma_f32_16x16x32_bf16(af, bp[(1 * 8 + ks) * 64 + lane], acc[1], 0, 0, 0);
  }

  float av[2], dv[2];
  #pragma unroll
  for (int ci = 0; ci < 2; ++ci) {
    av[ci] = a_src1[ci * 16 + (lane & 15)];
    dv[ci] = a_dst1[ci * 16 + (lane & 15)];
  }
  #pragma unroll
  for (int r = 0; r < 4; ++r) {
    int gr = rbase + (lane >> 4) * 4 + r;
    float ps = acc[0][r] * av[0] + acc[1][r] * av[1];
    float pd = acc[0][r] * dv[0] + acc[1][r] * dv[1];
    #pragma unroll
    for (int off = 1; off < 16; off <<= 1) {
      ps += __shfl_xor(ps, off);
      pd += __shfl_xor(pd, off);
    }
    if (gr < M) {
      h1bf[(size_t)gr * 32 + (lane & 15)]      = f2bf(acc[0][r]);
      h1bf[(size_t)gr * 32 + 16 + (lane & 15)] = f2bf(acc[1][r]);
      if ((lane & 15) == 0) { as1[gr] = ps; ad1[gr] = pd; }
    }
  }
}

// ------------------------- CSR build ---------------------------------------
__global__ __launch_bounds__(256) void hist_kernel(
    const int* __restrict__ dsts, int* __restrict__ deg, int E, int N) {
  int e = blockIdx.x * 256 + threadIdx.x;
  if (e >= E + N) return;
  int d = (e < E) ? dsts[e] : e - E;
  atomicAdd(&deg[d], 1);
}

__global__ __launch_bounds__(256) void scan_block_kernel(
    const int* __restrict__ deg, int* __restrict__ excl,
    int* __restrict__ bsum, int N) {
  __shared__ int tmp[256];
  int i = blockIdx.x * 256 + threadIdx.x;
  int v = (i < N) ? deg[i] : 0;
  tmp[threadIdx.x] = v;
  __syncthreads();
  #pragma unroll
  for (int off = 1; off < 256; off <<= 1) {
    int t = (threadIdx.x >= off) ? tmp[threadIdx.x - off] : 0;
    __syncthreads();
    tmp[threadIdx.x] += t;
    __syncthreads();
  }
  if (i < N) excl[i] = tmp[threadIdx.x] - v;
  if (threadIdx.x == 255) bsum[blockIdx.x] = tmp[255];
}

__global__ __launch_bounds__(256) void scan_bsum_kernel(int* __restrict__ bsum, int NB) {
  __shared__ int tmp[256];
  int i = threadIdx.x;
  int v = (i < NB) ? bsum[i] : 0;
  tmp[i] = v;
  __syncthreads();
  #pragma unroll
  for (int off = 1; off < 256; off <<= 1) {
    int t = (i >= off) ? tmp[i - off] : 0;
    __syncthreads();
    tmp[i] += t;
    __syncthreads();
  }
  if (i < NB) bsum[i] = tmp[i] - v;
}

__global__ __launch_bounds__(256) void scan_add_kernel(
    int* __restrict__ rowptr, const int* __restrict__ bsum,
    int* __restrict__ cursor, int N, int Etot) {
  int i = blockIdx.x * 256 + threadIdx.x;
  if (i < N) {
    int r = rowptr[i] + bsum[blockIdx.x];
    rowptr[i] = r;
    cursor[i] = r;
  }
  if (i == 0) rowptr[N] = Etot;
}

// scatter (after gemm0): CSR src/dst + layer-0 edge weights (4 heads)
__global__ __launch_bounds__(256) void scatter_kernel(
    const int* __restrict__ srcs, const int* __restrict__ dsts,
    int* __restrict__ cursor, const float* __restrict__ as0,
    const float* __restrict__ ad0, int* __restrict__ csr_src,
    int* __restrict__ csr_dst, float* __restrict__ ew0, int E, int N) {
  int e = blockIdx.x * 256 + threadIdx.x;
  if (e >= E + N) return;
  int s, d;
  if (e < E) { s = srcs[e]; d = dsts[e]; } else { s = d = e - E; }
  int pos = atomicAdd(&cursor[d], 1);
  csr_src[pos] = s;
  csr_dst[pos] = d;
  float4 a = *reinterpret_cast<const float4*>(&as0[s * 4]);
  float4 b = *reinterpret_cast<const float4*>(&ad0[d * 4]);
  float4 w;
  w.x = __expf(lrelu(a.x + b.x));
  w.y = __expf(lrelu(a.y + b.y));
  w.z = __expf(lrelu(a.z + b.z));
  w.w = __expf(lrelu(a.w + b.w));
  *reinterpret_cast<float4*>(&ew0[(size_t)pos * 4]) = w;
}

// layer-1 edge weights (after gemm1), CSR-slot-parallel
__global__ __launch_bounds__(256) void ew1_kernel(
    const int* __restrict__ csr_src, const int* __restrict__ csr_dst,
    const float* __restrict__ as1, const float* __restrict__ ad1,
    float* __restrict__ ew1, int Etot) {
  int i = blockIdx.x * 256 + threadIdx.x;
  if (i >= Etot) return;
  ew1[i] = __expf(lrelu(as1[csr_src[i]] + ad1[csr_dst[i]]));
}

// ------------- layer-0 aggregate: one wave per node, unroll x4 -------------
// R6-proven structure; weights loaded from ew0 (sequential per row).
__global__ __launch_bounds__(256) void agg0_kernel(
    const int* __restrict__ rowptr, const int* __restrict__ csr_src,
    const float* __restrict__ ew0, const unsigned short* __restrict__ h0bf,
    const float* __restrict__ b0,
    const float* __restrict__ gamma, const float* __restrict__ beta,
    const float* __restrict__ mean, const float* __restrict__ var,
    unsigned short* __restrict__ outbf, int N) {
  const int lane = threadIdx.x & 63;
  const int wid = threadIdx.x >> 6;
  const int n = blockIdx.x * 4 + wid;
  if (n >= N) return;
  const int h = lane >> 4;
  const int beg = rowptr[n], end = rowptr[n + 1];
  float4 acc = make_float4(0.f, 0.f, 0.f, 0.f);
  float wsum = 0.f;
  int i = beg;
  for (; i + 4 <= end; i += 4) {
    int s0 = csr_src[i + 0], s1 = csr_src[i + 1],
        s2 = csr_src[i + 2], s3 = csr_src[i + 3];
    float w0 = ew0[(size_t)(i + 0) * 4 + h], w1 = ew0[(size_t)(i + 1) * 4 + h],
          w2 = ew0[(size_t)(i + 2) * 4 + h], w3 = ew0[(size_t)(i + 3) * 4 + h];
    ushort4 v0 = *reinterpret_cast<const ushort4*>(&h0bf[(size_t)s0 * 256 + lane * 4]);
    ushort4 v1 = *reinterpret_cast<const ushort4*>(&h0bf[(size_t)s1 * 256 + lane * 4]);
    ushort4 v2 = *reinterpret_cast<const ushort4*>(&h0bf[(size_t)s2 * 256 + lane * 4]);
    ushort4 v3 = *reinterpret_cast<const ushort4*>(&h0bf[(size_t)s3 * 256 + lane * 4]);
    wsum += (w0 + w1) + (w2 + w3);
    acc.x += w0 * bf2f(v0.x) + w1 * bf2f(v1.x) + w2 * bf2f(v2.x) + w3 * bf2f(v3.x);
    acc.y += w0 * bf2f(v0.y) + w1 * bf2f(v1.y) + w2 * bf2f(v2.y) + w3 * bf2f(v3.y);
    acc.z += w0 * bf2f(v0.z) + w1 * bf2f(v1.z) + w2 * bf2f(v2.z) + w3 * bf2f(v3.z);
    acc.w += w0 * bf2f(v0.w) + w1 * bf2f(v1.w) + w2 * bf2f(v2.w) + w3 * bf2f(v3.w);
  }
  for (; i < end; ++i) {
    int s = csr_src[i];
    float w = ew0[(size_t)i * 4 + h];
    wsum += w;
    ushort4 v = *reinterpret_cast<const ushort4*>(&h0bf[(size_t)s * 256 + lane * 4]);
    acc.x += w * bf2f(v.x); acc.y += w * bf2f(v.y);
    acc.z += w * bf2f(v.z); acc.w += w * bf2f(v.w);
  }
  float inv = 1.0f / wsum;
  int j = lane * 4;
  float4 bb = *reinterpret_cast<const float4*>(&b0[j]);
  float4 mu = *reinterpret_cast<const float4*>(&mean[j]);
  float4 gg = *reinterpret_cast<const float4*>(&gamma[j]);
  float4 vv = *reinterpret_cast<const float4*>(&var[j]);
  float4 be = *reinterpret_cast<const float4*>(&beta[j]);
  float4 o;
  o.x = (acc.x * inv + bb.x - mu.x) * (gg.x * rsqrtf(vv.x + BN_EPS)) + be.x;
  o.y = (acc.y * inv + bb.y - mu.y) * (gg.y * rsqrtf(vv.y + BN_EPS)) + be.y;
  o.z = (acc.z * inv + bb.z - mu.z) * (gg.z * rsqrtf(vv.z + BN_EPS)) + be.z;
  o.w = (acc.w * inv + bb.w - mu.w) * (gg.w * rsqrtf(vv.w + BN_EPS)) + be.w;
  ushort4 ob;
  ob.x = f2bf(fmaxf(o.x, 0.f)); ob.y = f2bf(fmaxf(o.y, 0.f));
  ob.z = f2bf(fmaxf(o.z, 0.f)); ob.w = f2bf(fmaxf(o.w, 0.f));
  *reinterpret_cast<ushort4*>(&outbf[(size_t)n * 256 + j]) = ob;
}

// ------------- layer-1 aggregate: one wave per node, 2 edges parallel ------
// R6-proven structure; weights from ew1 (sequential per row).
__global__ __launch_bounds__(256) void agg1_kernel(
    const int* __restrict__ rowptr, const int* __restrict__ csr_src,
    const float* __restrict__ ew1, const unsigned short* __restrict__ h1bf,
    const float* __restrict__ b1, float* __restrict__ out, int N) {
  const int t = threadIdx.x;
  const int lane = t & 63;
  const int w = t >> 6;
  const int n = blockIdx.x * 4 + w;
  if (n >= N) return;
  const int c = lane & 31;
  const int half = lane >> 5;
  const int beg = rowptr[n], end = rowptr[n + 1];
  float acc = 0.f, wsum = 0.f;
  int i = beg + half;
  for (; i + 6 < end; i += 8) {
    int s0 = csr_src[i + 0], s1 = csr_src[i + 2],
        s2 = csr_src[i + 4], s3 = csr_src[i + 6];
    float w0 = ew1[i + 0], w1 = ew1[i + 2], w2 = ew1[i + 4], w3 = ew1[i + 6];
    unsigned short u0 = h1bf[(size_t)s0 * 32 + c];
    unsigned short u1 = h1bf[(size_t)s1 * 32 + c];
    unsigned short u2 = h1bf[(size_t)s2 * 32 + c];
    unsigned short u3 = h1bf[(size_t)s3 * 32 + c];
    wsum += (w0 + w1) + (w2 + w3);
    acc += w0 * bf2f(u0) + w1 * bf2f(u1) + w2 * bf2f(u2) + w3 * bf2f(u3);
  }
  for (; i < end; i += 2) {
    int s = csr_src[i];
    float wgt = ew1[i];
    wsum += wgt;
    acc += wgt * bf2f(h1bf[(size_t)s * 32 + c]);
  }
  acc += __shfl_xor(acc, 32);
  wsum += __shfl_xor(wsum, 32);
  if (half == 0) out[(size_t)n * 32 + c] = acc / wsum + b1[c];
}

// ------------- graph-sum reduce over out[N,32] -----------------------------
__global__ __launch_bounds__(256) void gsum_kernel(
    const float* __restrict__ out, float* __restrict__ gsum, int N) {
  __shared__ float red[8][32];
  const int t = threadIdx.x;
  const int c = t & 31;
  float s = 0.f;
  const size_t total = (size_t)N * 32;
  for (size_t j = (size_t)blockIdx.x * 256 + t; j < total;
       j += (size_t)gridDim.x * 256)
    s += out[j];
  red[t >> 5][c] = s;
  __syncthreads();
  if (t < 32) {
    float v = 0.f;
    #pragma unroll
    for (int i = 0; i < 8; ++i) v += red[i][t];
    atomicAdd(&gsum[t], v);
  }
}

// ------------- prediction head (1 block, 64 threads) -----------------------
__global__ void pred_kernel(
    const float* __restrict__ gsum, const float* __restrict__ hW1,
    const float* __restrict__ hb1, const float* __restrict__ hW2,
    const float* __restrict__ hb2, float* __restrict__ out, int N) {
  int j = threadIdx.x;
  float invN = 1.0f / (float)N;
  float acc = hb1[j];
  #pragma unroll
  for (int c = 0; c < 32; ++c) acc += (gsum[c] * invN) * hW1[c * 64 + j];
  acc = fmaxf(acc, 0.f);
  float v = acc * hW2[j];
  #pragma unroll
  for (int off = 1; off < 64; off <<= 1) v += __shfl_xor(v, off);
  if (j == 0) out[(size_t)N * 32] = v + hb2[0];
}

// ---------------------------------------------------------------------------
extern "C" void kernel_launch(void* const* d_in, const int* in_sizes, int n_in,
                              void* d_out, int out_size, void* d_ws, size_t ws_size,
                              hipStream_t stream) {
  const float* x       = (const float*)d_in[0];
  const int*   ei      = (const int*)d_in[1];
  const float* W0      = (const float*)d_in[2];
  const float* a_src0  = (const float*)d_in[3];
  const float* a_dst0  = (const float*)d_in[4];
  const float* b0      = (const float*)d_in[5];
  const float* bn_g    = (const float*)d_in[6];
  const float* bn_b    = (const float*)d_in[7];
  const float* bn_m    = (const float*)d_in[8];
  const float* bn_v    = (const float*)d_in[9];
  const float* W1      = (const float*)d_in[10];
  const float* a_src1  = (const float*)d_in[11];
  const float* a_dst1  = (const float*)d_in[12];
  const float* b1      = (const float*)d_in[13];
  const float* hW1     = (const float*)d_in[14];
  const float* hb1     = (const float*)d_in[15];
  const float* hW2     = (const float*)d_in[16];
  const float* hb2     = (const float*)d_in[17];

  const int N = in_sizes[0] / 128;
  const int E = in_sizes[1] / 2;
  const int Etot = E + N;
  const int* srcs = ei;
  const int* dsts = ei + E;
  const int NB = (N + 255) / 256;

  float* out = (float*)d_out;

  // workspace layout (4-byte units)
  float* ws = (float*)d_ws;
  size_t off = 0;
  unsigned short* h0bf   = (unsigned short*)(ws + off); off += (size_t)N * 128;
  unsigned short* agg0bf = (unsigned short*)(ws + off); off += (size_t)N * 128;
  unsigned short* h1bf   = (unsigned short*)(ws + off); off += (size_t)N * 16;
  unsigned short* w0sw   = (unsigned short*)(ws + off); off += 16384;
  unsigned short* w1sw   = (unsigned short*)(ws + off); off += 4096;
  float* as0    = ws + off; off += (size_t)N * 4;
  float* ad0    = ws + off; off += (size_t)N * 4;
  float* as1    = ws + off; off += (size_t)N;
  float* ad1    = ws + off; off += (size_t)N;
  int* rowptr   = (int*)(ws + off); off += (size_t)N + 1;
  int* cursor   = (int*)(ws + off); off += (size_t)N;
  int* bsum     = (int*)(ws + off); off += 256;
  int* csr_src  = (int*)(ws + off); off += (size_t)Etot;
  int* csr_dst  = (int*)(ws + off); off += (size_t)Etot;
  float* ew0    = ws + off; off += (size_t)Etot * 4;
  float* ew1    = ws + off; off += (size_t)Etot;
  // --- zeroed region (contiguous): deg + gsum ---
  size_t zoff = off;
  int* deg      = (int*)(ws + off); off += (size_t)N;
  float* gsum   = ws + off; off += 32;

  hipMemsetAsync(ws + zoff, 0, (off - zoff) * sizeof(float), stream);

  auto cdiv = [](long a, long b) { return (int)((a + b - 1) / b); };

  // CSR skeleton (graph-only; scatter deferred until as0/ad0 exist)
  hist_kernel<<<cdiv(Etot, 256), 256, 0, stream>>>(dsts, deg, E, N);
  scan_block_kernel<<<NB, 256, 0, stream>>>(deg, rowptr, bsum, N);
  scan_bsum_kernel<<<1, 256, 0, stream>>>(bsum, NB);
  scan_add_kernel<<<NB, 256, 0, stream>>>(rowptr, bsum, cursor, N, Etot);

  // weight swizzles (W0 + W1)
  w_swizzle_kernel<<<160, 256, 0, stream>>>(W0, W1, w0sw, w1sw);

  // layer 0
  gemm0_mfma_kernel<<<cdiv(N, 64), 256, 0, stream>>>(
      x, w0sw, a_src0, a_dst0, h0bf, as0, ad0, N);
  scatter_kernel<<<cdiv(Etot, 256), 256, 0, stream>>>(
      srcs, dsts, cursor, as0, ad0, csr_src, csr_dst, ew0, E, N);
  agg0_kernel<<<cdiv(N, 4), 256, 0, stream>>>(rowptr, csr_src, ew0, h0bf,
                                              b0, bn_g, bn_b, bn_m, bn_v, agg0bf, N);

  // layer 1
  gemm1_mfma_kernel<<<cdiv(N, 64), 256, 0, stream>>>(
      agg0bf, w1sw, a_src1, a_dst1, h1bf, as1, ad1, N);
  ew1_kernel<<<cdiv(Etot, 256), 256, 0, stream>>>(csr_src, csr_dst, as1, ad1, ew1, Etot);
  agg1_kernel<<<cdiv(N, 4), 256, 0, stream>>>(rowptr, csr_src, ew1, h1bf, b1, out, N);

  // graph mean + head
  gsum_kernel<<<128, 256, 0, stream>>>(out, gsum, N);
  pred_kernel<<<1, 64, 0, stream>>>(gsum, hW1, hb1, hW2, hb2, out, N);
}

// Round 10
// 343.438 us; speedup vs baseline: 1.0037x; 1.0037x over previous
//
#include <hip/hip_runtime.h>

// ---------------------------------------------------------------------------
// SupervisedGATEncoder: 2-layer GAT (4 heads x 64 -> BN -> ReLU -> 1 head x 32)
// + graph-mean prediction head.
//
// R10: (a) agg0 unroll x8 (8 gathers in flight; L3-latency-bound per R9
// counters); (b) agg1 -> 4 edges x 16 lanes x 2 cols (uint loads), x4 unroll,
// uniform predication (no divergent-loop shuffle broadcasts — R7/R8 lesson).
// Edge weights stay materialized (ew0/ew1, R9-proven). Rest as R9.
// ---------------------------------------------------------------------------

#define NEG_SLOPE 0.2f
#define BN_EPS 1e-5f

typedef __attribute__((ext_vector_type(8))) short bf16x8;
typedef __attribute__((ext_vector_type(4))) float f32x4;

__device__ __forceinline__ float bf2f(unsigned short u) {
  return __uint_as_float((unsigned)u << 16);
}
__device__ __forceinline__ unsigned short f2bf(float f) {
  unsigned u = __float_as_uint(f);
  u += 0x7fff + ((u >> 16) & 1);   // round-to-nearest-even
  return (unsigned short)(u >> 16);
}
__device__ __forceinline__ float lrelu(float x) {
  return x > 0.f ? x : NEG_SLOPE * x;
}

// ------------- W0 + W1 -> bf16, swizzled to MFMA B-fragment order ----------
__global__ __launch_bounds__(256) void w_swizzle_kernel(
    const float* __restrict__ W0, const float* __restrict__ W1,
    unsigned short* __restrict__ w0sw, unsigned short* __restrict__ w1sw) {
  int o = blockIdx.x * 256 + threadIdx.x;
  if (o < 32768) {
    int j = o & 7, l = (o >> 3) & 63, ks = (o >> 9) & 3,
        ci = (o >> 11) & 3, h = (o >> 13) & 3;
    int row = ks * 32 + (l >> 4) * 8 + j;
    int col = h * 64 + ci * 16 + (l & 15);
    w0sw[o] = f2bf(W0[row * 256 + col]);
  } else if (o < 40960) {
    int o2 = o - 32768;
    int j = o2 & 7, l = (o2 >> 3) & 63, ks = (o2 >> 9) & 7, ci = (o2 >> 12) & 1;
    int row = ks * 32 + (l >> 4) * 8 + j;
    int col = ci * 16 + (l & 15);
    w1sw[o2] = f2bf(W1[row * 32 + col]);
  }
}

// ---------------- GEMM0 (MFMA): h0[M,256] = x[M,128] @ W0[128,256] ---------
__global__ __launch_bounds__(256) void gemm0_mfma_kernel(
    const float* __restrict__ x, const unsigned short* __restrict__ w0sw,
    const float* __restrict__ a_src0, const float* __restrict__ a_dst0,
    unsigned short* __restrict__ h0bf, float* __restrict__ as0,
    float* __restrict__ ad0, int M) {
  __shared__ unsigned short Asw[16 * 64 * 8];   // 16 KB
  const int t = threadIdx.x;
  const int lane = t & 63;
  const int h = t >> 6;            // wave id == head
  const int row0 = blockIdx.x * 64;

  #pragma unroll
  for (int i = 0; i < 8; ++i) {
    int q = t + 256 * i;
    int r = q >> 5, c4 = q & 31;
    int gr = row0 + r;
    float4 v = make_float4(0.f, 0.f, 0.f, 0.f);
    if (gr < M) v = *reinterpret_cast<const float4*>(&x[(size_t)gr * 128 + c4 * 4]);
    int ks = c4 >> 3;
    int lane_hi = (c4 >> 1) & 3;
    int j0 = (c4 & 1) * 4;
    int slot = (r >> 4) * 4 + ks;
    int dlane = (r & 15) + 16 * lane_hi;
    ushort4 o;
    o.x = f2bf(v.x); o.y = f2bf(v.y); o.z = f2bf(v.z); o.w = f2bf(v.w);
    *reinterpret_cast<ushort4*>(&Asw[(slot * 64 + dlane) * 8 + j0]) = o;
  }
  __syncthreads();

  f32x4 acc[4][4] = {};
  const bf16x8* wp = reinterpret_cast<const bf16x8*>(w0sw);
  #pragma unroll
  for (int ks = 0; ks < 4; ++ks) {
    bf16x8 bfrag[4];
    #pragma unroll
    for (int ci = 0; ci < 4; ++ci)
      bfrag[ci] = wp[(h * 16 + ci * 4 + ks) * 64 + lane];
    #pragma unroll
    for (int ri = 0; ri < 4; ++ri) {
      bf16x8 af = *reinterpret_cast<const bf16x8*>(&Asw[((ri * 4 + ks) * 64 + lane) * 8]);
      #pragma unroll
      for (int ci = 0; ci < 4; ++ci)
        acc[ri][ci] = __builtin_amdgcn_mfma_f32_16x16x32_bf16(af, bfrag[ci], acc[ri][ci], 0, 0, 0);
    }
  }

  float av[4], dv[4];
  #pragma unroll
  for (int ci = 0; ci < 4; ++ci) {
    av[ci] = a_src0[h * 64 + ci * 16 + (lane & 15)];
    dv[ci] = a_dst0[h * 64 + ci * 16 + (lane & 15)];
  }
  const int mrow = (lane >> 4) * 4;
  #pragma unroll
  for (int ri = 0; ri < 4; ++ri) {
    #pragma unroll
    for (int r = 0; r < 4; ++r) {
      int gr = row0 + ri * 16 + mrow + r;
      float ps = acc[ri][0][r] * av[0] + acc[ri][1][r] * av[1] +
                 acc[ri][2][r] * av[2] + acc[ri][3][r] * av[3];
      float pd = acc[ri][0][r] * dv[0] + acc[ri][1][r] * dv[1] +
                 acc[ri][2][r] * dv[2] + acc[ri][3][r] * dv[3];
      #pragma unroll
      for (int off = 1; off < 16; off <<= 1) {
        ps += __shfl_xor(ps, off);
        pd += __shfl_xor(pd, off);
      }
      if (gr < M) {
        #pragma unroll
        for (int ci = 0; ci < 4; ++ci)
          h0bf[(size_t)gr * 256 + h * 64 + ci * 16 + (lane & 15)] = f2bf(acc[ri][ci][r]);
        if ((lane & 15) == 0) { as0[gr * 4 + h] = ps; ad0[gr * 4 + h] = pd; }
      }
    }
  }
}

// ------------- GEMM1 (MFMA): h1[M,32] = agg0bf[M,256] @ W1[256,32] ---------
__global__ __launch_bounds__(256) void gemm1_mfma_kernel(
    const unsigned short* __restrict__ agg0bf,
    const unsigned short* __restrict__ w1sw,
    const float* __restrict__ a_src1, const float* __restrict__ a_dst1,
    unsigned short* __restrict__ h1bf, float* __restrict__ as1,
    float* __restrict__ ad1, int M) {
  const int t = threadIdx.x;
  const int lane = t & 63;
  const int w = t >> 6;
  const int rbase = blockIdx.x * 64 + w * 16;
  const int arow = rbase + (lane & 15);
  const int ar = arow < M ? arow : M - 1;   // clamp: A row m only affects C row m
  const bf16x8* ap = reinterpret_cast<const bf16x8*>(agg0bf) + (size_t)ar * 32;
  const bf16x8* bp = reinterpret_cast<const bf16x8*>(w1sw);

  f32x4 acc[2] = {};
  #pragma unroll
  for (int ks = 0; ks < 8; ++ks) {
    bf16x8 af = ap[ks * 4 + (lane >> 4)];
    acc[0] = __builtin_amdgcn_mfma_f32_16x16x32_bf16(af, bp[(0 * 8 + ks) * 64 + lane], acc[0], 0, 0, 0);
    acc[1] = __builtin_amdgcn_mfma_f32_16x16x32_bf16(af, bp[(1 * 8 + ks) * 64 + lane], acc[1], 0, 0, 0);
  }

  float av[2], dv[2];
  #pragma unroll
  for (int ci = 0; ci < 2; ++ci) {
    av[ci] = a_src1[ci * 16 + (lane & 15)];
    dv[ci] = a_dst1[ci * 16 + (lane & 15)];
  }
  #pragma unroll
  for (int r = 0; r < 4; ++r) {
    int gr = rbase + (lane >> 4) * 4 + r;
    float ps = acc[0][r] * av[0] + acc[1][r] * av[1];
    float pd = acc[0][r] * dv[0] + acc[1][r] * dv[1];
    #pragma unroll
    for (int off = 1; off < 16; off <<= 1) {
      ps += __shfl_xor(ps, off);
      pd += __shfl_xor(pd, off);
    }
    if (gr < M) {
      h1bf[(size_t)gr * 32 + (lane & 15)]      = f2bf(acc[0][r]);
      h1bf[(size_t)gr * 32 + 16 + (lane & 15)] = f2bf(acc[1][r]);
      if ((lane & 15) == 0) { as1[gr] = ps; ad1[gr] = pd; }
    }
  }
}

// ------------------------- CSR build ---------------------------------------
__global__ __launch_bounds__(256) void hist_kernel(
    const int* __restrict__ dsts, int* __restrict__ deg, int E, int N) {
  int e = blockIdx.x * 256 + threadIdx.x;
  if (e >= E + N) return;
  int d = (e < E) ? dsts[e] : e - E;
  atomicAdd(&deg[d], 1);
}

__global__ __launch_bounds__(256) void scan_block_kernel(
    const int* __restrict__ deg, int* __restrict__ excl,
    int* __restrict__ bsum, int N) {
  __shared__ int tmp[256];
  int i = blockIdx.x * 256 + threadIdx.x;
  int v = (i < N) ? deg[i] : 0;
  tmp[threadIdx.x] = v;
  __syncthreads();
  #pragma unroll
  for (int off = 1; off < 256; off <<= 1) {
    int t = (threadIdx.x >= off) ? tmp[threadIdx.x - off] : 0;
    __syncthreads();
    tmp[threadIdx.x] += t;
    __syncthreads();
  }
  if (i < N) excl[i] = tmp[threadIdx.x] - v;
  if (threadIdx.x == 255) bsum[blockIdx.x] = tmp[255];
}

__global__ __launch_bounds__(256) void scan_bsum_kernel(int* __restrict__ bsum, int NB) {
  __shared__ int tmp[256];
  int i = threadIdx.x;
  int v = (i < NB) ? bsum[i] : 0;
  tmp[i] = v;
  __syncthreads();
  #pragma unroll
  for (int off = 1; off < 256; off <<= 1) {
    int t = (i >= off) ? tmp[i - off] : 0;
    __syncthreads();
    tmp[i] += t;
    __syncthreads();
  }
  if (i < NB) bsum[i] = tmp[i] - v;
}

__global__ __launch_bounds__(256) void scan_add_kernel(
    int* __restrict__ rowptr, const int* __restrict__ bsum,
    int* __restrict__ cursor, int N, int Etot) {
  int i = blockIdx.x * 256 + threadIdx.x;
  if (i < N) {
    int r = rowptr[i] + bsum[blockIdx.x];
    rowptr[i] = r;
    cursor[i] = r;
  }
  if (i == 0) rowptr[N] = Etot;
}

// scatter (after gemm0): CSR src/dst + layer-0 edge weights (4 heads)
__global__ __launch_bounds__(256) void scatter_kernel(
    const int* __restrict__ srcs, const int* __restrict__ dsts,
    int* __restrict__ cursor, const float* __restrict__ as0,
    const float* __restrict__ ad0, int* __restrict__ csr_src,
    int* __restrict__ csr_dst, float* __restrict__ ew0, int E, int N) {
  int e = blockIdx.x * 256 + threadIdx.x;
  if (e >= E + N) return;
  int s, d;
  if (e < E) { s = srcs[e]; d = dsts[e]; } else { s = d = e - E; }
  int pos = atomicAdd(&cursor[d], 1);
  csr_src[pos] = s;
  csr_dst[pos] = d;
  float4 a = *reinterpret_cast<const float4*>(&as0[s * 4]);
  float4 b = *reinterpret_cast<const float4*>(&ad0[d * 4]);
  float4 w;
  w.x = __expf(lrelu(a.x + b.x));
  w.y = __expf(lrelu(a.y + b.y));
  w.z = __expf(lrelu(a.z + b.z));
  w.w = __expf(lrelu(a.w + b.w));
  *reinterpret_cast<float4*>(&ew0[(size_t)pos * 4]) = w;
}

// layer-1 edge weights (after gemm1), CSR-slot-parallel
__global__ __launch_bounds__(256) void ew1_kernel(
    const int* __restrict__ csr_src, const int* __restrict__ csr_dst,
    const float* __restrict__ as1, const float* __restrict__ ad1,
    float* __restrict__ ew1, int Etot) {
  int i = blockIdx.x * 256 + threadIdx.x;
  if (i >= Etot) return;
  ew1[i] = __expf(lrelu(as1[csr_src[i]] + ad1[csr_dst[i]]));
}

// ------------- layer-0 aggregate: one wave per node, unroll x8 -------------
__global__ __launch_bounds__(256) void agg0_kernel(
    const int* __restrict__ rowptr, const int* __restrict__ csr_src,
    const float* __restrict__ ew0, const unsigned short* __restrict__ h0bf,
    const float* __restrict__ b0,
    const float* __restrict__ gamma, const float* __restrict__ beta,
    const float* __restrict__ mean, const float* __restrict__ var,
    unsigned short* __restrict__ outbf, int N) {
  const int lane = threadIdx.x & 63;
  const int wid = threadIdx.x >> 6;
  const int n = blockIdx.x * 4 + wid;
  if (n >= N) return;
  const int h = lane >> 4;
  const int beg = rowptr[n], end = rowptr[n + 1];
  float4 acc = make_float4(0.f, 0.f, 0.f, 0.f);
  float wsum = 0.f;
  int i = beg;
  for (; i + 8 <= end; i += 8) {
    int s[8]; float w[8]; ushort4 v[8];
    #pragma unroll
    for (int k = 0; k < 8; ++k) s[k] = csr_src[i + k];
    #pragma unroll
    for (int k = 0; k < 8; ++k) w[k] = ew0[(size_t)(i + k) * 4 + h];
    #pragma unroll
    for (int k = 0; k < 8; ++k)
      v[k] = *reinterpret_cast<const ushort4*>(&h0bf[(size_t)s[k] * 256 + lane * 4]);
    #pragma unroll
    for (int k = 0; k < 8; ++k) {
      wsum += w[k];
      acc.x += w[k] * bf2f(v[k].x);
      acc.y += w[k] * bf2f(v[k].y);
      acc.z += w[k] * bf2f(v[k].z);
      acc.w += w[k] * bf2f(v[k].w);
    }
  }
  for (; i < end; ++i) {
    int s = csr_src[i];
    float w = ew0[(size_t)i * 4 + h];
    wsum += w;
    ushort4 v = *reinterpret_cast<const ushort4*>(&h0bf[(size_t)s * 256 + lane * 4]);
    acc.x += w * bf2f(v.x); acc.y += w * bf2f(v.y);
    acc.z += w * bf2f(v.z); acc.w += w * bf2f(v.w);
  }
  float inv = 1.0f / wsum;
  int j = lane * 4;
  float4 bb = *reinterpret_cast<const float4*>(&b0[j]);
  float4 mu = *reinterpret_cast<const float4*>(&mean[j]);
  float4 gg = *reinterpret_cast<const float4*>(&gamma[j]);
  float4 vv = *reinterpret_cast<const float4*>(&var[j]);
  float4 be = *reinterpret_cast<const float4*>(&beta[j]);
  float4 o;
  o.x = (acc.x * inv + bb.x - mu.x) * (gg.x * rsqrtf(vv.x + BN_EPS)) + be.x;
  o.y = (acc.y * inv + bb.y - mu.y) * (gg.y * rsqrtf(vv.y + BN_EPS)) + be.y;
  o.z = (acc.z * inv + bb.z - mu.z) * (gg.z * rsqrtf(vv.z + BN_EPS)) + be.z;
  o.w = (acc.w * inv + bb.w - mu.w) * (gg.w * rsqrtf(vv.w + BN_EPS)) + be.w;
  ushort4 ob;
  ob.x = f2bf(fmaxf(o.x, 0.f)); ob.y = f2bf(fmaxf(o.y, 0.f));
  ob.z = f2bf(fmaxf(o.z, 0.f)); ob.w = f2bf(fmaxf(o.w, 0.f));
  *reinterpret_cast<ushort4*>(&outbf[(size_t)n * 256 + j]) = ob;
}

// ------------- layer-1 aggregate: 4 edges x 16 lanes x 2 cols --------------
// lane: eg = lane>>4 (edge group), c2 = lane&15 (col pair 2*c2,2*c2+1).
// Uniform predication (clamped index + zero weight) — no divergent loops.
// x4 unroll -> 16 edge-rows in flight per wave. Merge via shfl_xor(16/32).
__global__ __launch_bounds__(256) void agg1_kernel(
    const int* __restrict__ rowptr, const int* __restrict__ csr_src,
    const float* __restrict__ ew1, const unsigned short* __restrict__ h1bf,
    const float* __restrict__ b1, float* __restrict__ out, int N) {
  const int t = threadIdx.x;
  const int lane = t & 63;
  const int w = t >> 6;
  const int n = blockIdx.x * 4 + w;
  if (n >= N) return;
  const int eg = lane >> 4;
  const int c2 = lane & 15;
  const int beg = rowptr[n], end = rowptr[n + 1];
  float accx = 0.f, accy = 0.f, wsum = 0.f;
  for (int i = beg; i < end; i += 16) {
    int e[4]; int s[4]; float wg[4]; unsigned u[4];
    #pragma unroll
    for (int k = 0; k < 4; ++k) {
      e[k] = i + k * 4 + eg;
      int ee = e[k] < end ? e[k] : end - 1;
      s[k] = csr_src[ee];
    }
    #pragma unroll
    for (int k = 0; k < 4; ++k)
      wg[k] = (e[k] < end) ? ew1[e[k]] : 0.f;
    #pragma unroll
    for (int k = 0; k < 4; ++k)
      u[k] = *reinterpret_cast<const unsigned*>(&h1bf[(size_t)s[k] * 32 + c2 * 2]);
    #pragma unroll
    for (int k = 0; k < 4; ++k) {
      wsum += wg[k];
      accx += wg[k] * bf2f((unsigned short)(u[k] & 0xffff));
      accy += wg[k] * bf2f((unsigned short)(u[k] >> 16));
    }
  }
  accx += __shfl_xor(accx, 16); accx += __shfl_xor(accx, 32);
  accy += __shfl_xor(accy, 16); accy += __shfl_xor(accy, 32);
  wsum += __shfl_xor(wsum, 16); wsum += __shfl_xor(wsum, 32);
  if (lane < 16) {
    float inv = 1.0f / wsum;
    float2 o;
    o.x = accx * inv + b1[c2 * 2];
    o.y = accy * inv + b1[c2 * 2 + 1];
    *reinterpret_cast<float2*>(&out[(size_t)n * 32 + c2 * 2]) = o;
  }
}

// ------------- graph-sum reduce over out[N,32] -----------------------------
__global__ __launch_bounds__(256) void gsum_kernel(
    const float* __restrict__ out, float* __restrict__ gsum, int N) {
  __shared__ float red[8][32];
  const int t = threadIdx.x;
  const int c = t & 31;
  float s = 0.f;
  const size_t total = (size_t)N * 32;
  for (size_t j = (size_t)blockIdx.x * 256 + t; j < total;
       j += (size_t)gridDim.x * 256)
    s += out[j];
  red[t >> 5][c] = s;
  __syncthreads();
  if (t < 32) {
    float v = 0.f;
    #pragma unroll
    for (int i = 0; i < 8; ++i) v += red[i][t];
    atomicAdd(&gsum[t], v);
  }
}

// ------------- prediction head (1 block, 64 threads) -----------------------
__global__ void pred_kernel(
    const float* __restrict__ gsum, const float* __restrict__ hW1,
    const float* __restrict__ hb1, const float* __restrict__ hW2,
    const float* __restrict__ hb2, float* __restrict__ out, int N) {
  int j = threadIdx.x;
  float invN = 1.0f / (float)N;
  float acc = hb1[j];
  #pragma unroll
  for (int c = 0; c < 32; ++c) acc += (gsum[c] * invN) * hW1[c * 64 + j];
  acc = fmaxf(acc, 0.f);
  float v = acc * hW2[j];
  #pragma unroll
  for (int off = 1; off < 64; off <<= 1) v += __shfl_xor(v, off);
  if (j == 0) out[(size_t)N * 32] = v + hb2[0];
}

// ---------------------------------------------------------------------------
extern "C" void kernel_launch(void* const* d_in, const int* in_sizes, int n_in,
                              void* d_out, int out_size, void* d_ws, size_t ws_size,
                              hipStream_t stream) {
  const float* x       = (const float*)d_in[0];
  const int*   ei      = (const int*)d_in[1];
  const float* W0      = (const float*)d_in[2];
  const float* a_src0  = (const float*)d_in[3];
  const float* a_dst0  = (const float*)d_in[4];
  const float* b0      = (const float*)d_in[5];
  const float* bn_g    = (const float*)d_in[6];
  const float* bn_b    = (const float*)d_in[7];
  const float* bn_m    = (const float*)d_in[8];
  const float* bn_v    = (const float*)d_in[9];
  const float* W1      = (const float*)d_in[10];
  const float* a_src1  = (const float*)d_in[11];
  const float* a_dst1  = (const float*)d_in[12];
  const float* b1      = (const float*)d_in[13];
  const float* hW1     = (const float*)d_in[14];
  const float* hb1     = (const float*)d_in[15];
  const float* hW2     = (const float*)d_in[16];
  const float* hb2     = (const float*)d_in[17];

  const int N = in_sizes[0] / 128;
  const int E = in_sizes[1] / 2;
  const int Etot = E + N;
  const int* srcs = ei;
  const int* dsts = ei + E;
  const int NB = (N + 255) / 256;

  float* out = (float*)d_out;

  // workspace layout (4-byte units)
  float* ws = (float*)d_ws;
  size_t off = 0;
  unsigned short* h0bf   = (unsigned short*)(ws + off); off += (size_t)N * 128;
  unsigned short* agg0bf = (unsigned short*)(ws + off); off += (size_t)N * 128;
  unsigned short* h1bf   = (unsigned short*)(ws + off); off += (size_t)N * 16;
  unsigned short* w0sw   = (unsigned short*)(ws + off); off += 16384;
  unsigned short* w1sw   = (unsigned short*)(ws + off); off += 4096;
  float* as0    = ws + off; off += (size_t)N * 4;
  float* ad0    = ws + off; off += (size_t)N * 4;
  float* as1    = ws + off; off += (size_t)N;
  float* ad1    = ws + off; off += (size_t)N;
  int* rowptr   = (int*)(ws + off); off += (size_t)N + 1;
  int* cursor   = (int*)(ws + off); off += (size_t)N;
  int* bsum     = (int*)(ws + off); off += 256;
  int* csr_src  = (int*)(ws + off); off += (size_t)Etot;
  int* csr_dst  = (int*)(ws + off); off += (size_t)Etot;
  float* ew0    = ws + off; off += (size_t)Etot * 4;
  float* ew1    = ws + off; off += (size_t)Etot;
  // --- zeroed region (contiguous): deg + gsum ---
  size_t zoff = off;
  int* deg      = (int*)(ws + off); off += (size_t)N;
  float* gsum   = ws + off; off += 32;

  hipMemsetAsync(ws + zoff, 0, (off - zoff) * sizeof(float), stream);

  auto cdiv = [](long a, long b) { return (int)((a + b - 1) / b); };

  // CSR skeleton (graph-only; scatter deferred until as0/ad0 exist)
  hist_kernel<<<cdiv(Etot, 256), 256, 0, stream>>>(dsts, deg, E, N);
  scan_block_kernel<<<NB, 256, 0, stream>>>(deg, rowptr, bsum, N);
  scan_bsum_kernel<<<1, 256, 0, stream>>>(bsum, NB);
  scan_add_kernel<<<NB, 256, 0, stream>>>(rowptr, bsum, cursor, N, Etot);

  // weight swizzles (W0 + W1)
  w_swizzle_kernel<<<160, 256, 0, stream>>>(W0, W1, w0sw, w1sw);

  // layer 0
  gemm0_mfma_kernel<<<cdiv(N, 64), 256, 0, stream>>>(
      x, w0sw, a_src0, a_dst0, h0bf, as0, ad0, N);
  scatter_kernel<<<cdiv(Etot, 256), 256, 0, stream>>>(
      srcs, dsts, cursor, as0, ad0, csr_src, csr_dst, ew0, E, N);
  agg0_kernel<<<cdiv(N, 4), 256, 0, stream>>>(rowptr, csr_src, ew0, h0bf,
                                              b0, bn_g, bn_b, bn_m, bn_v, agg0bf, N);

  // layer 1
  gemm1_mfma_kernel<<<cdiv(N, 64), 256, 0, stream>>>(
      agg0bf, w1sw, a_src1, a_dst1, h1bf, as1, ad1, N);
  ew1_kernel<<<cdiv(Etot, 256), 256, 0, stream>>>(csr_src, csr_dst, as1, ad1, ew1, Etot);
  agg1_kernel<<<cdiv(N, 4), 256, 0, stream>>>(rowptr, csr_src, ew1, h1bf, b1, out, N);

  // graph mean + head
  gsum_kernel<<<128, 256, 0, stream>>>(out, gsum, N);
  pred_kernel<<<1, 64, 0, stream>>>(gsum, hW1, hb1, hW2, hb2, out, N);
}